// Round 1
// baseline (867.196 us; speedup 1.0000x reference)
//
#include <hip/hip_runtime.h>

#define N_NODES 50000
#define N_EDGES 100000
#define NT 21
#define STEPS 6
#define BPT 40   // blocks per edge-type in k_msg

// ---------- helpers ----------
__device__ __forceinline__ float sigm(float x) { return 1.f / (1.f + __expf(-x)); }
__device__ __forceinline__ float tanh_f(float x) {
    float t = __expf(2.f * fabsf(x));
    return copysignf(1.f - 2.f / (t + 1.f), x);
}

// ---------- h0 = relu(node_emb[node_ids] @ proj_W + proj_b) ----------
__global__ __launch_bounds__(256) void k_proj(const int* __restrict__ node_ids,
                                              const float* __restrict__ node_emb,
                                              const float* __restrict__ W,   // [64][32]
                                              const float* __restrict__ b,   // [32]
                                              float* __restrict__ h) {
    int lane = threadIdx.x & 31;
    int n = blockIdx.x * 8 + (threadIdx.x >> 5);
    if (n >= N_NODES) return;
    float w[64];
#pragma unroll
    for (int i = 0; i < 64; ++i) w[i] = W[i * 32 + lane];
    int id = node_ids[n];
    const float* er = node_emb + id * 64;
    float e0 = er[lane];
    float e1 = er[32 + lane];
    float acc = b[lane];
#pragma unroll
    for (int i = 0; i < 32; ++i) acc += __shfl(e0, i, 32) * w[i];
#pragma unroll
    for (int i = 0; i < 32; ++i) acc += __shfl(e1, i, 32) * w[32 + i];
    h[n * 32 + lane] = fmaxf(acc, 0.f);
}

// ---------- W table: 21 matrices, Wt[t][i][o] ----------
// grid = NT*8 blocks of 128 threads; block computes one 128-wide chunk of the 1024 outputs
__global__ __launch_bounds__(128) void k_wtable(const float* __restrict__ edge_emb, // [21][16]
                                                const float* __restrict__ eW1,      // [16][128]
                                                const float* __restrict__ eb1,      // [128]
                                                const float* __restrict__ eW2,      // [128][1024]
                                                const float* __restrict__ eb2,      // [1024]
                                                float* __restrict__ Wt) {           // [21][1024]
    __shared__ float x[128];
    int t = blockIdx.x >> 3, c = blockIdx.x & 7;
    int tid = threadIdx.x;
    float acc = eb1[tid];
#pragma unroll
    for (int i = 0; i < 16; ++i) acc += edge_emb[t * 16 + i] * eW1[i * 128 + tid];
    x[tid] = fmaxf(acc, 0.f);
    __syncthreads();
    int j = c * 128 + tid;
    float a = eb2[j];
#pragma unroll 8
    for (int i = 0; i < 128; ++i) a += x[i] * eW2[i * 1024 + j];
    Wt[t * 1024 + j] = a;
}

// ---------- bucket edges by type ----------
__global__ __launch_bounds__(256) void k_count(const int* __restrict__ eid, int* __restrict__ cnt) {
    __shared__ int lc[32];
    if (threadIdx.x < 32) lc[threadIdx.x] = 0;
    __syncthreads();
    int e = blockIdx.x * 256 + threadIdx.x;
    if (e < N_EDGES) atomicAdd(&lc[eid[e]], 1);
    __syncthreads();
    if (threadIdx.x < NT) {
        int v = lc[threadIdx.x];
        if (v) atomicAdd(&cnt[threadIdx.x], v);
    }
}

__global__ void k_scan(const int* __restrict__ cnt, int* __restrict__ base, int* __restrict__ cur) {
    if (threadIdx.x == 0 && blockIdx.x == 0) {
        int r = 0;
        for (int t = 0; t < NT; ++t) { base[t] = r; cur[t] = r; r += cnt[t]; }
    }
}

__global__ __launch_bounds__(256) void k_fill(const int* __restrict__ eid,
                                              int* __restrict__ cur, int* __restrict__ perm) {
    int e = blockIdx.x * 256 + threadIdx.x;
    int lane = threadIdx.x & 63;
    int t = (e < N_EDGES) ? eid[e] : -1;
    unsigned long long lt = (lane == 63) ? 0x7fffffffffffffffULL : ((1ULL << lane) - 1ULL);
    for (int tt = 0; tt < NT; ++tt) {
        unsigned long long mask = __ballot(t == tt);
        if (mask) {
            int leader = __ffsll((unsigned long long)mask) - 1;
            int p0 = 0;
            if (lane == leader) p0 = atomicAdd(&cur[tt], __popcll(mask));
            p0 = __shfl(p0, leader);
            if (t == tt) perm[p0 + __popcll(mask & lt)] = e;
        }
    }
}

// ---------- message + scatter: agg[dst] += h[src] @ W[type] ----------
// grid = NT*BPT; block handles one type, W column cached in 32 regs/lane
__global__ __launch_bounds__(256) void k_msg(const int* __restrict__ perm,
                                             const int* __restrict__ base,
                                             const int* __restrict__ cnt,
                                             const int* __restrict__ src,
                                             const int* __restrict__ dst,
                                             const float* __restrict__ Wt,
                                             const float* __restrict__ h,
                                             float* __restrict__ agg) {
    int t = blockIdx.x / BPT, sub = blockIdx.x % BPT;
    int lane = threadIdx.x & 31, g = threadIdx.x >> 5;
    const float* wp = Wt + t * 1024;
    float w[32];
#pragma unroll
    for (int i = 0; i < 32; ++i) w[i] = wp[i * 32 + lane];
    int n = cnt[t], b0 = base[t];
    for (int idx = sub * 8 + g; idx < n; idx += BPT * 8) {
        int e = perm[b0 + idx];
        int s = src[e], d = dst[e];
        float hv = h[s * 32 + lane];
        float acc = 0.f;
#pragma unroll
        for (int i = 0; i < 32; ++i) acc += __shfl(hv, i, 32) * w[i];
        atomicAdd(&agg[d * 32 + lane], acc);
    }
}

// ---------- GRU: 4 threads/node, each owns 8 of the 32 output features ----------
__global__ __launch_bounds__(256) void k_gru(const float* __restrict__ Wih,  // [96][32]
                                             const float* __restrict__ Whh,  // [96][32]
                                             const float* __restrict__ bih,  // [96]
                                             const float* __restrict__ bhh,  // [96]
                                             const float* __restrict__ cb,   // [32]
                                             float* __restrict__ agg,
                                             float* __restrict__ h) {
    __shared__ float wiT[32 * 96];  // [i][k]
    __shared__ float whT[32 * 96];
    for (int u = threadIdx.x; u < 3072; u += 256) {
        int k = u >> 5, i = u & 31;
        wiT[i * 96 + k] = Wih[u];
        whT[i * 96 + k] = Whh[u];
    }
    __syncthreads();
    int gtid = blockIdx.x * 256 + threadIdx.x;
    int n = gtid >> 2, j = gtid & 3;
    if (n >= N_NODES) return;
    float* ap = agg + n * 32;
    float m[32], hv[32];
#pragma unroll
    for (int q = 0; q < 8; ++q) {
        float4 a = ((const float4*)ap)[q];
        float4 c = ((const float4*)cb)[q];
        m[4 * q + 0] = fmaxf(a.x + c.x, 0.f);
        m[4 * q + 1] = fmaxf(a.y + c.y, 0.f);
        m[4 * q + 2] = fmaxf(a.z + c.z, 0.f);
        m[4 * q + 3] = fmaxf(a.w + c.w, 0.f);
    }
#pragma unroll
    for (int q = 0; q < 8; ++q) {
        float4 x = ((const float4*)(h + n * 32))[q];
        hv[4 * q + 0] = x.x; hv[4 * q + 1] = x.y;
        hv[4 * q + 2] = x.z; hv[4 * q + 3] = x.w;
    }
    // zero our slice of agg for the next step (same-wave: all loads above precede these stores)
    float4 z4 = make_float4(0.f, 0.f, 0.f, 0.f);
    ((float4*)ap)[2 * j] = z4;
    ((float4*)ap)[2 * j + 1] = z4;

    const int kb = j * 8;
    float acc[8];
    // r gate (k = kb..kb+7)
#pragma unroll
    for (int q = 0; q < 8; ++q) acc[q] = 0.f;
#pragma unroll
    for (int i = 0; i < 32; ++i) {
        float mi = m[i], hi = hv[i];
        const float* wr = wiT + i * 96 + kb;
        const float* hr = whT + i * 96 + kb;
#pragma unroll
        for (int q = 0; q < 8; ++q) acc[q] += mi * wr[q] + hi * hr[q];
    }
    float rg[8];
#pragma unroll
    for (int q = 0; q < 8; ++q) rg[q] = sigm(acc[q] + bih[kb + q] + bhh[kb + q]);
    // n gate (k = 64+kb..): needs input- and hidden-parts separate
    float aI[8], aH[8];
#pragma unroll
    for (int q = 0; q < 8; ++q) { aI[q] = 0.f; aH[q] = 0.f; }
#pragma unroll
    for (int i = 0; i < 32; ++i) {
        float mi = m[i], hi = hv[i];
        const float* wr = wiT + i * 96 + 64 + kb;
        const float* hr = whT + i * 96 + 64 + kb;
#pragma unroll
        for (int q = 0; q < 8; ++q) { aI[q] += mi * wr[q]; aH[q] += hi * hr[q]; }
    }
    float nn[8];
#pragma unroll
    for (int q = 0; q < 8; ++q)
        nn[q] = tanh_f(aI[q] + bih[64 + kb + q] + rg[q] * (aH[q] + bhh[64 + kb + q]));
    // z gate (k = 32+kb..)
#pragma unroll
    for (int q = 0; q < 8; ++q) acc[q] = 0.f;
#pragma unroll
    for (int i = 0; i < 32; ++i) {
        float mi = m[i], hi = hv[i];
        const float* wr = wiT + i * 96 + 32 + kb;
        const float* hr = whT + i * 96 + 32 + kb;
#pragma unroll
        for (int q = 0; q < 8; ++q) acc[q] += mi * wr[q] + hi * hr[q];
    }
    float out[8];
#pragma unroll
    for (int q = 0; q < 8; ++q) {
        float z = sigm(acc[q] + bih[32 + kb + q] + bhh[32 + kb + q]);
        out[q] = (1.f - z) * nn[q] + z * hv[kb + q];
    }
    float4 o0 = make_float4(out[0], out[1], out[2], out[3]);
    float4 o1 = make_float4(out[4], out[5], out[6], out[7]);
    ((float4*)(h + n * 32 + kb))[0] = o0;
    ((float4*)(h + n * 32 + kb))[1] = o1;
}

extern "C" void kernel_launch(void* const* d_in, const int* in_sizes, int n_in,
                              void* d_out, int out_size, void* d_ws, size_t ws_size,
                              hipStream_t stream) {
    const int*   node_ids  = (const int*)d_in[0];
    const int*   edge_ids  = (const int*)d_in[1];
    const int*   src       = (const int*)d_in[2];
    const int*   dst       = (const int*)d_in[3];
    const float* node_emb  = (const float*)d_in[4];
    const float* edge_emb  = (const float*)d_in[5];
    const float* proj_W    = (const float*)d_in[6];
    const float* proj_b    = (const float*)d_in[7];
    const float* eW1       = (const float*)d_in[8];
    const float* eb1       = (const float*)d_in[9];
    const float* eW2       = (const float*)d_in[10];
    const float* eb2       = (const float*)d_in[11];
    const float* conv_bias = (const float*)d_in[12];
    const float* gWih      = (const float*)d_in[13];
    const float* gWhh      = (const float*)d_in[14];
    const float* gbih      = (const float*)d_in[15];
    const float* gbhh      = (const float*)d_in[16];

    float* h = (float*)d_out;  // [N,32] fp32 — output buffer doubles as hidden state
    char* ws = (char*)d_ws;
    float* agg = (float*)ws;                                   // 6,400,000 B
    float* Wt  = (float*)(ws + 6400 * 1024);                   // 86,016 B
    int*   cnt = (int*)(ws + 6400 * 1024 + 128 * 1024);
    int*   base = cnt + 32;
    int*   cur  = cnt + 64;
    int*   perm = cnt + 128;                                   // 400,000 B

    hipMemsetAsync(agg, 0, (size_t)N_NODES * 32 * sizeof(float), stream);
    hipMemsetAsync(cnt, 0, 32 * sizeof(int), stream);

    k_proj<<<(N_NODES + 7) / 8, 256, 0, stream>>>(node_ids, node_emb, proj_W, proj_b, h);
    k_wtable<<<NT * 8, 128, 0, stream>>>(edge_emb, eW1, eb1, eW2, eb2, Wt);
    k_count<<<(N_EDGES + 255) / 256, 256, 0, stream>>>(edge_ids, cnt);
    k_scan<<<1, 64, 0, stream>>>(cnt, base, cur);
    k_fill<<<(N_EDGES + 255) / 256, 256, 0, stream>>>(edge_ids, cur, perm);

    for (int s = 0; s < STEPS; ++s) {
        k_msg<<<NT * BPT, 256, 0, stream>>>(perm, base, cnt, src, dst, Wt, h, agg);
        k_gru<<<(N_NODES * 4 + 255) / 256, 256, 0, stream>>>(gWih, gWhh, gbih, gbhh, conv_bias, agg, h);
    }
}

// Round 4
// 548.734 us; speedup vs baseline: 1.5804x; 1.5804x over previous
//
#include <hip/hip_runtime.h>

#define N_NODES 50000
#define N_EDGES 100000
#define NT 21
#define STEPS 6
#define BPT 40    // blocks per edge-type in k_msg
#define NB 100    // blocks for counting sort
#define EPB 1000  // edges per block (NB*EPB == N_EDGES)

// ---------- helpers ----------
__device__ __forceinline__ float sigm(float x) { return 1.f / (1.f + __expf(-x)); }
__device__ __forceinline__ float tanh_f(float x) {
    float t = __expf(2.f * fabsf(x));
    return copysignf(1.f - 2.f / (t + 1.f), x);
}

// ---------- h0 = relu(node_emb[node_ids] @ proj_W + proj_b) ----------
__global__ __launch_bounds__(256) void k_proj(const int* __restrict__ node_ids,
                                              const float* __restrict__ node_emb,
                                              const float* __restrict__ W,   // [64][32]
                                              const float* __restrict__ b,   // [32]
                                              float* __restrict__ h) {
    int lane = threadIdx.x & 31;
    int n = blockIdx.x * 8 + (threadIdx.x >> 5);
    if (n >= N_NODES) return;
    float w[64];
#pragma unroll
    for (int i = 0; i < 64; ++i) w[i] = W[i * 32 + lane];
    int id = node_ids[n];
    const float* er = node_emb + id * 64;
    float e0 = er[lane];
    float e1 = er[32 + lane];
    float acc = b[lane];
#pragma unroll
    for (int i = 0; i < 32; ++i) acc += __shfl(e0, i, 32) * w[i];
#pragma unroll
    for (int i = 0; i < 32; ++i) acc += __shfl(e1, i, 32) * w[32 + i];
    h[n * 32 + lane] = fmaxf(acc, 0.f);
}

// ---------- W table: 21 matrices, Wt[t][i][o] ----------
__global__ __launch_bounds__(128) void k_wtable(const float* __restrict__ edge_emb, // [21][16]
                                                const float* __restrict__ eW1,      // [16][128]
                                                const float* __restrict__ eb1,      // [128]
                                                const float* __restrict__ eW2,      // [128][1024]
                                                const float* __restrict__ eb2,      // [1024]
                                                float* __restrict__ Wt) {           // [21][1024]
    __shared__ float x[128];
    int t = blockIdx.x >> 3, c = blockIdx.x & 7;
    int tid = threadIdx.x;
    float acc = eb1[tid];
#pragma unroll
    for (int i = 0; i < 16; ++i) acc += edge_emb[t * 16 + i] * eW1[i * 128 + tid];
    x[tid] = fmaxf(acc, 0.f);
    __syncthreads();
    int j = c * 128 + tid;
    float a = eb2[j];
#pragma unroll 8
    for (int i = 0; i < 128; ++i) a += x[i] * eW2[i * 1024 + j];
    Wt[t * 1024 + j] = a;
}

// ---------- counting sort, pass A: per-block LDS histogram ----------
__global__ __launch_bounds__(256) void k_hist(const int* __restrict__ eid,
                                              int* __restrict__ hist) {   // [NB][NT]
    __shared__ int lc[NT];
    if (threadIdx.x < NT) lc[threadIdx.x] = 0;
    __syncthreads();
    int e0 = blockIdx.x * EPB;
#pragma unroll
    for (int k = 0; k < EPB / 256 + 1; ++k) {
        int e = e0 + k * 256 + threadIdx.x;
        if (e < e0 + EPB) atomicAdd(&lc[eid[e]], 1);
    }
    __syncthreads();
    if (threadIdx.x < NT) hist[blockIdx.x * NT + threadIdx.x] = lc[threadIdx.x];
}

// ---------- pass B: per-type prefix over blocks + type base scan (1 tiny block) ----------
__global__ void k_offs(const int* __restrict__ hist,  // [NB][NT]
                       int* __restrict__ offs,        // [NB][NT]
                       int* __restrict__ cnt,         // [NT]
                       int* __restrict__ base) {      // [NT]
    __shared__ int tot[NT];
    int t = threadIdx.x;
    if (t < NT) {
        int run = 0;
        for (int b = 0; b < NB; ++b) { offs[b * NT + t] = run; run += hist[b * NT + t]; }
        tot[t] = run;
        cnt[t] = run;
    }
    __syncthreads();
    if (t == 0) {
        int r = 0;
        for (int tt = 0; tt < NT; ++tt) { base[tt] = r; r += tot[tt]; }
    }
}

// ---------- pass C: scatter edges to perm at precomputed offsets (no global atomics) ----------
__global__ __launch_bounds__(256) void k_fill2(const int* __restrict__ eid,
                                               const int* __restrict__ offs,
                                               const int* __restrict__ base,
                                               int* __restrict__ perm) {
    __shared__ int cur[NT];
    int b = blockIdx.x;
    if (threadIdx.x < NT) cur[threadIdx.x] = base[threadIdx.x] + offs[b * NT + threadIdx.x];
    __syncthreads();
    int e0 = b * EPB;
#pragma unroll
    for (int k = 0; k < EPB / 256 + 1; ++k) {
        int e = e0 + k * 256 + threadIdx.x;
        if (e < e0 + EPB) {
            int r = atomicAdd(&cur[eid[e]], 1);
            perm[r] = e;
        }
    }
}

// ---------- message + scatter: agg[dst] += h[src] @ W[type] ----------
__global__ __launch_bounds__(256) void k_msg(const int* __restrict__ perm,
                                             const int* __restrict__ base,
                                             const int* __restrict__ cnt,
                                             const int* __restrict__ src,
                                             const int* __restrict__ dst,
                                             const float* __restrict__ Wt,
                                             const float* __restrict__ h,
                                             float* __restrict__ agg) {
    int t = blockIdx.x / BPT, sub = blockIdx.x % BPT;
    int lane = threadIdx.x & 31, g = threadIdx.x >> 5;
    const float* wp = Wt + t * 1024;
    float w[32];
#pragma unroll
    for (int i = 0; i < 32; ++i) w[i] = wp[i * 32 + lane];
    int n = cnt[t], b0 = base[t];
    for (int idx = sub * 8 + g; idx < n; idx += BPT * 8) {
        int e = perm[b0 + idx];
        int s = src[e], d = dst[e];
        float hv = h[s * 32 + lane];
        float acc = 0.f;
#pragma unroll
        for (int i = 0; i < 32; ++i) acc += __shfl(hv, i, 32) * w[i];
        atomicAdd(&agg[d * 32 + lane], acc);
    }
}

// ---------- GRU: 4 threads/node, each owns 8 of the 32 output features ----------
__global__ __launch_bounds__(256) void k_gru(const float* __restrict__ Wih,  // [96][32]
                                             const float* __restrict__ Whh,  // [96][32]
                                             const float* __restrict__ bih,  // [96]
                                             const float* __restrict__ bhh,  // [96]
                                             const float* __restrict__ cb,   // [32]
                                             float* __restrict__ agg,
                                             float* __restrict__ h) {
    __shared__ float wiT[32 * 96];  // [i][k]
    __shared__ float whT[32 * 96];
    for (int u = threadIdx.x; u < 3072; u += 256) {
        int k = u >> 5, i = u & 31;
        wiT[i * 96 + k] = Wih[u];
        whT[i * 96 + k] = Whh[u];
    }
    __syncthreads();
    int gtid = blockIdx.x * 256 + threadIdx.x;
    int n = gtid >> 2, j = gtid & 3;
    if (n >= N_NODES) return;
    float* ap = agg + n * 32;
    float m[32], hv[32];
#pragma unroll
    for (int q = 0; q < 8; ++q) {
        float4 a = ((const float4*)ap)[q];
        float4 c = ((const float4*)cb)[q];
        m[4 * q + 0] = fmaxf(a.x + c.x, 0.f);
        m[4 * q + 1] = fmaxf(a.y + c.y, 0.f);
        m[4 * q + 2] = fmaxf(a.z + c.z, 0.f);
        m[4 * q + 3] = fmaxf(a.w + c.w, 0.f);
    }
#pragma unroll
    for (int q = 0; q < 8; ++q) {
        float4 x = ((const float4*)(h + n * 32))[q];
        hv[4 * q + 0] = x.x; hv[4 * q + 1] = x.y;
        hv[4 * q + 2] = x.z; hv[4 * q + 3] = x.w;
    }
    // zero our slice of agg for the next step (same-wave: loads above precede these stores)
    float4 z4 = make_float4(0.f, 0.f, 0.f, 0.f);
    ((float4*)ap)[2 * j] = z4;
    ((float4*)ap)[2 * j + 1] = z4;

    const int kb = j * 8;
    float acc[8];
    // r gate
#pragma unroll
    for (int q = 0; q < 8; ++q) acc[q] = 0.f;
#pragma unroll
    for (int i = 0; i < 32; ++i) {
        float mi = m[i], hi = hv[i];
        const float* wr = wiT + i * 96 + kb;
        const float* hr = whT + i * 96 + kb;
#pragma unroll
        for (int q = 0; q < 8; ++q) acc[q] += mi * wr[q] + hi * hr[q];
    }
    float rg[8];
#pragma unroll
    for (int q = 0; q < 8; ++q) rg[q] = sigm(acc[q] + bih[kb + q] + bhh[kb + q]);
    // n gate: input- and hidden-parts separate
    float aI[8], aH[8];
#pragma unroll
    for (int q = 0; q < 8; ++q) { aI[q] = 0.f; aH[q] = 0.f; }
#pragma unroll
    for (int i = 0; i < 32; ++i) {
        float mi = m[i], hi = hv[i];
        const float* wr = wiT + i * 96 + 64 + kb;
        const float* hr = whT + i * 96 + 64 + kb;
#pragma unroll
        for (int q = 0; q < 8; ++q) { aI[q] += mi * wr[q]; aH[q] += hi * hr[q]; }
    }
    float nn[8];
#pragma unroll
    for (int q = 0; q < 8; ++q)
        nn[q] = tanh_f(aI[q] + bih[64 + kb + q] + rg[q] * (aH[q] + bhh[64 + kb + q]));
    // z gate
#pragma unroll
    for (int q = 0; q < 8; ++q) acc[q] = 0.f;
#pragma unroll
    for (int i = 0; i < 32; ++i) {
        float mi = m[i], hi = hv[i];
        const float* wr = wiT + i * 96 + 32 + kb;
        const float* hr = whT + i * 96 + 32 + kb;
#pragma unroll
        for (int q = 0; q < 8; ++q) acc[q] += mi * wr[q] + hi * hr[q];
    }
    float out[8];
#pragma unroll
    for (int q = 0; q < 8; ++q) {
        float z = sigm(acc[q] + bih[32 + kb + q] + bhh[32 + kb + q]);
        out[q] = (1.f - z) * nn[q] + z * hv[kb + q];
    }
    float4 o0 = make_float4(out[0], out[1], out[2], out[3]);
    float4 o1 = make_float4(out[4], out[5], out[6], out[7]);
    ((float4*)(h + n * 32 + kb))[0] = o0;
    ((float4*)(h + n * 32 + kb))[1] = o1;
}

extern "C" void kernel_launch(void* const* d_in, const int* in_sizes, int n_in,
                              void* d_out, int out_size, void* d_ws, size_t ws_size,
                              hipStream_t stream) {
    const int*   node_ids  = (const int*)d_in[0];
    const int*   edge_ids  = (const int*)d_in[1];
    const int*   src       = (const int*)d_in[2];
    const int*   dst       = (const int*)d_in[3];
    const float* node_emb  = (const float*)d_in[4];
    const float* edge_emb  = (const float*)d_in[5];
    const float* proj_W    = (const float*)d_in[6];
    const float* proj_b    = (const float*)d_in[7];
    const float* eW1       = (const float*)d_in[8];
    const float* eb1       = (const float*)d_in[9];
    const float* eW2       = (const float*)d_in[10];
    const float* eb2       = (const float*)d_in[11];
    const float* conv_bias = (const float*)d_in[12];
    const float* gWih      = (const float*)d_in[13];
    const float* gWhh      = (const float*)d_in[14];
    const float* gbih      = (const float*)d_in[15];
    const float* gbhh      = (const float*)d_in[16];

    float* h = (float*)d_out;  // [N,32] fp32 — output buffer doubles as hidden state
    char* ws = (char*)d_ws;
    float* agg  = (float*)ws;                                  // 6,400,000 B
    float* Wt   = (float*)(ws + 6400 * 1024);                  // 86,016 B
    int*   hist = (int*)(ws + 6400 * 1024 + 128 * 1024);       // NB*NT = 2100
    int*   offs = hist + NB * NT;                              // 2100
    int*   cnt  = offs + NB * NT;                              // 32
    int*   base = cnt + 32;                                    // 32
    int*   perm = base + 32;                                   // 100,000

    hipMemsetAsync(agg, 0, (size_t)N_NODES * 32 * sizeof(float), stream);

    k_proj<<<(N_NODES + 7) / 8, 256, 0, stream>>>(node_ids, node_emb, proj_W, proj_b, h);
    k_wtable<<<NT * 8, 128, 0, stream>>>(edge_emb, eW1, eb1, eW2, eb2, Wt);
    k_hist<<<NB, 256, 0, stream>>>(edge_ids, hist);
    k_offs<<<1, 64, 0, stream>>>(hist, offs, cnt, base);
    k_fill2<<<NB, 256, 0, stream>>>(edge_ids, offs, base, perm);

    for (int s = 0; s < STEPS; ++s) {
        k_msg<<<NT * BPT, 256, 0, stream>>>(perm, base, cnt, src, dst, Wt, h, agg);
        k_gru<<<(N_NODES * 4 + 255) / 256, 256, 0, stream>>>(gWih, gWhh, gbih, gbhh, conv_bias, agg, h);
    }
}

// Round 6
// 488.208 us; speedup vs baseline: 1.7763x; 1.1240x over previous
//
#include <hip/hip_runtime.h>

#define N_NODES 50000
#define N_EDGES 100000
#define NT 21
#define STEPS 6
#define BPT 40    // blocks per edge-type in k_msg
#define NB 100    // blocks for counting sort
#define EPB 1000  // edges per block (NB*EPB == N_EDGES)

// ---------- helpers ----------
__device__ __forceinline__ float sigm(float x) { return 1.f / (1.f + __expf(-x)); }
__device__ __forceinline__ float tanh_f(float x) {
    float t = __expf(2.f * fabsf(x));
    return copysignf(1.f - 2.f / (t + 1.f), x);
}

// ---------- h0 = relu(node_emb[node_ids] @ proj_W + proj_b) ----------
__global__ __launch_bounds__(256) void k_proj(const int* __restrict__ node_ids,
                                              const float* __restrict__ node_emb,
                                              const float* __restrict__ W,   // [64][32]
                                              const float* __restrict__ b,   // [32]
                                              float* __restrict__ h) {
    int lane = threadIdx.x & 31;
    int n = blockIdx.x * 8 + (threadIdx.x >> 5);
    if (n >= N_NODES) return;
    float w[64];
#pragma unroll
    for (int i = 0; i < 64; ++i) w[i] = W[i * 32 + lane];
    int id = node_ids[n];
    const float* er = node_emb + id * 64;
    float e0 = er[lane];
    float e1 = er[32 + lane];
    float acc = b[lane];
#pragma unroll
    for (int i = 0; i < 32; ++i) acc += __shfl(e0, i, 32) * w[i];
#pragma unroll
    for (int i = 0; i < 32; ++i) acc += __shfl(e1, i, 32) * w[32 + i];
    h[n * 32 + lane] = fmaxf(acc, 0.f);
}

// ---------- W table: 21 matrices, Wt[t][i][o] ----------
__global__ __launch_bounds__(128) void k_wtable(const float* __restrict__ edge_emb, // [21][16]
                                                const float* __restrict__ eW1,      // [16][128]
                                                const float* __restrict__ eb1,      // [128]
                                                const float* __restrict__ eW2,      // [128][1024]
                                                const float* __restrict__ eb2,      // [1024]
                                                float* __restrict__ Wt) {           // [21][1024]
    __shared__ float x[128];
    int t = blockIdx.x >> 3, c = blockIdx.x & 7;
    int tid = threadIdx.x;
    float acc = eb1[tid];
#pragma unroll
    for (int i = 0; i < 16; ++i) acc += edge_emb[t * 16 + i] * eW1[i * 128 + tid];
    x[tid] = fmaxf(acc, 0.f);
    __syncthreads();
    int j = c * 128 + tid;
    float a = eb2[j];
#pragma unroll 8
    for (int i = 0; i < 128; ++i) a += x[i] * eW2[i * 1024 + j];
    Wt[t * 1024 + j] = a;
}

// ---------- counting sort, pass A: per-block LDS histogram ----------
__global__ __launch_bounds__(256) void k_hist(const int* __restrict__ eid,
                                              int* __restrict__ hist) {   // [NB][NT]
    __shared__ int lc[NT];
    if (threadIdx.x < NT) lc[threadIdx.x] = 0;
    __syncthreads();
    int e0 = blockIdx.x * EPB;
#pragma unroll
    for (int k = 0; k < EPB / 256 + 1; ++k) {
        int e = e0 + k * 256 + threadIdx.x;
        if (e < e0 + EPB) atomicAdd(&lc[eid[e]], 1);
    }
    __syncthreads();
    if (threadIdx.x < NT) hist[blockIdx.x * NT + threadIdx.x] = lc[threadIdx.x];
}

// ---------- pass B: per-type prefix over blocks + type base scan (1 tiny block) ----------
__global__ void k_offs(const int* __restrict__ hist,  // [NB][NT]
                       int* __restrict__ offs,        // [NB][NT]
                       int* __restrict__ cnt,         // [NT]
                       int* __restrict__ base) {      // [NT]
    __shared__ int tot[NT];
    int t = threadIdx.x;
    if (t < NT) {
        int run = 0;
        for (int b = 0; b < NB; ++b) { offs[b * NT + t] = run; run += hist[b * NT + t]; }
        tot[t] = run;
        cnt[t] = run;
    }
    __syncthreads();
    if (t == 0) {
        int r = 0;
        for (int tt = 0; tt < NT; ++tt) { base[tt] = r; r += tot[tt]; }
    }
}

// ---------- pass C: scatter edges to perm at precomputed offsets (no global atomics) ----------
__global__ __launch_bounds__(256) void k_fill2(const int* __restrict__ eid,
                                               const int* __restrict__ offs,
                                               const int* __restrict__ base,
                                               int* __restrict__ perm) {
    __shared__ int cur[NT];
    int b = blockIdx.x;
    if (threadIdx.x < NT) cur[threadIdx.x] = base[threadIdx.x] + offs[b * NT + threadIdx.x];
    __syncthreads();
    int e0 = b * EPB;
#pragma unroll
    for (int k = 0; k < EPB / 256 + 1; ++k) {
        int e = e0 + k * 256 + threadIdx.x;
        if (e < e0 + EPB) {
            int r = atomicAdd(&cur[eid[e]], 1);
            perm[r] = e;
        }
    }
}

// ---------- message + scatter: agg[dst] += h[src] @ W[type] ----------
__global__ __launch_bounds__(256) void k_msg(const int* __restrict__ perm,
                                             const int* __restrict__ base,
                                             const int* __restrict__ cnt,
                                             const int* __restrict__ src,
                                             const int* __restrict__ dst,
                                             const float* __restrict__ Wt,
                                             const float* __restrict__ h,
                                             float* __restrict__ agg) {
    int t = blockIdx.x / BPT, sub = blockIdx.x % BPT;
    int lane = threadIdx.x & 31, g = threadIdx.x >> 5;
    const float* wp = Wt + t * 1024;
    float w[32];
#pragma unroll
    for (int i = 0; i < 32; ++i) w[i] = wp[i * 32 + lane];
    int n = cnt[t], b0 = base[t];
    for (int idx = sub * 8 + g; idx < n; idx += BPT * 8) {
        int e = perm[b0 + idx];
        int s = src[e], d = dst[e];
        float hv = h[s * 32 + lane];
        float acc = 0.f;
#pragma unroll
        for (int i = 0; i < 32; ++i) acc += __shfl(hv, i, 32) * w[i];
        atomicAdd(&agg[d * 32 + lane], acc);
    }
}

// ---------- GRU v2: 2 nodes/thread, 8 threads/node-pair, fused gate i-loop ----------
// LDS layout [i][k] stride 96 (16B-aligned rows); conflict-free transpose stage
// (lane writes bank t&31); reads are float4 at banks (4j..4j+3)%32 — disjoint
// across j-groups, broadcast within. agg-zero + h-write at kernel end (all
// threads sharing a node row are in one wave; stores follow loads in program
// order; same-pointer aliasing pins the compiler's ordering).
__global__ __launch_bounds__(256) void k_gru(const float* __restrict__ Wih,  // [96][32]
                                             const float* __restrict__ Whh,  // [96][32]
                                             const float* __restrict__ bih,  // [96]
                                             const float* __restrict__ bhh,  // [96]
                                             const float* __restrict__ cb,   // [32]
                                             float* __restrict__ agg,
                                             float* __restrict__ h) {
    __shared__ float wiT[32 * 96];  // [i][k]
    __shared__ float whT[32 * 96];
    int t = threadIdx.x;
#pragma unroll
    for (int kk = 0; kk < 3; ++kk)
#pragma unroll
        for (int it = 0; it < 4; ++it) {
            int k = (t & 31) + 32 * kk;
            int i = (t >> 5) + 8 * it;
            wiT[i * 96 + k] = Wih[k * 32 + i];   // bank = k%32 = t&31: 2 lanes/bank, free
            whT[i * 96 + k] = Whh[k * 32 + i];
        }
    __syncthreads();

    int gtid = blockIdx.x * 256 + t;
    int p = gtid >> 3;                 // node pair
    if (p >= N_NODES / 2) return;
    int j = gtid & 7, kb = j * 4;      // this thread's 4 output features

    float* a0 = agg + (size_t)(2 * p) * 32;
    float* a1 = a0 + 32;
    float* h0p = h + (size_t)(2 * p) * 32;
    float* h1p = h0p + 32;

    float accR0[4] = {0, 0, 0, 0}, accR1[4] = {0, 0, 0, 0};
    float accZ0[4] = {0, 0, 0, 0}, accZ1[4] = {0, 0, 0, 0};
    float accI0[4] = {0, 0, 0, 0}, accI1[4] = {0, 0, 0, 0};
    float accH0[4] = {0, 0, 0, 0}, accH1[4] = {0, 0, 0, 0};

#pragma unroll
    for (int c = 0; c < 8; ++c) {
        float4 cb4 = ((const float4*)cb)[c];
        float4 ma = ((const float4*)a0)[c];
        float4 mb = ((const float4*)a1)[c];
        float4 ha = ((const float4*)h0p)[c];
        float4 hb = ((const float4*)h1p)[c];
        float m0[4] = {fmaxf(ma.x + cb4.x, 0.f), fmaxf(ma.y + cb4.y, 0.f),
                       fmaxf(ma.z + cb4.z, 0.f), fmaxf(ma.w + cb4.w, 0.f)};
        float m1[4] = {fmaxf(mb.x + cb4.x, 0.f), fmaxf(mb.y + cb4.y, 0.f),
                       fmaxf(mb.z + cb4.z, 0.f), fmaxf(mb.w + cb4.w, 0.f)};
        float h0v[4] = {ha.x, ha.y, ha.z, ha.w};
        float h1v[4] = {hb.x, hb.y, hb.z, hb.w};
#pragma unroll
        for (int e = 0; e < 4; ++e) {
            int i = 4 * c + e;
            const float* wb = wiT + i * 96 + kb;
            const float* vb = whT + i * 96 + kb;
            float4 wiR = *(const float4*)(wb);
            float4 whR = *(const float4*)(vb);
            float4 wiZ = *(const float4*)(wb + 32);
            float4 whZ = *(const float4*)(vb + 32);
            float4 wiN = *(const float4*)(wb + 64);
            float4 whN = *(const float4*)(vb + 64);
            float mi0 = m0[e], mi1 = m1[e], hi0 = h0v[e], hi1 = h1v[e];
            accR0[0] += mi0 * wiR.x + hi0 * whR.x;
            accR0[1] += mi0 * wiR.y + hi0 * whR.y;
            accR0[2] += mi0 * wiR.z + hi0 * whR.z;
            accR0[3] += mi0 * wiR.w + hi0 * whR.w;
            accR1[0] += mi1 * wiR.x + hi1 * whR.x;
            accR1[1] += mi1 * wiR.y + hi1 * whR.y;
            accR1[2] += mi1 * wiR.z + hi1 * whR.z;
            accR1[3] += mi1 * wiR.w + hi1 * whR.w;
            accZ0[0] += mi0 * wiZ.x + hi0 * whZ.x;
            accZ0[1] += mi0 * wiZ.y + hi0 * whZ.y;
            accZ0[2] += mi0 * wiZ.z + hi0 * whZ.z;
            accZ0[3] += mi0 * wiZ.w + hi0 * whZ.w;
            accZ1[0] += mi1 * wiZ.x + hi1 * whZ.x;
            accZ1[1] += mi1 * wiZ.y + hi1 * whZ.y;
            accZ1[2] += mi1 * wiZ.z + hi1 * whZ.z;
            accZ1[3] += mi1 * wiZ.w + hi1 * whZ.w;
            accI0[0] += mi0 * wiN.x;  accH0[0] += hi0 * whN.x;
            accI0[1] += mi0 * wiN.y;  accH0[1] += hi0 * whN.y;
            accI0[2] += mi0 * wiN.z;  accH0[2] += hi0 * whN.z;
            accI0[3] += mi0 * wiN.w;  accH0[3] += hi0 * whN.w;
            accI1[0] += mi1 * wiN.x;  accH1[0] += hi1 * whN.x;
            accI1[1] += mi1 * wiN.y;  accH1[1] += hi1 * whN.y;
            accI1[2] += mi1 * wiN.z;  accH1[2] += hi1 * whN.z;
            accI1[3] += mi1 * wiN.w;  accH1[3] += hi1 * whN.w;
        }
    }

    // re-load own h chunk (only this lane writes it later; load precedes all stores)
    float4 hv0 = ((const float4*)h0p)[j];
    float4 hv1 = ((const float4*)h1p)[j];
    float hs0[4] = {hv0.x, hv0.y, hv0.z, hv0.w};
    float hs1[4] = {hv1.x, hv1.y, hv1.z, hv1.w};

    float out0[4], out1[4];
#pragma unroll
    for (int q = 0; q < 4; ++q) {
        float bR = bih[kb + q] + bhh[kb + q];
        float bZ = bih[32 + kb + q] + bhh[32 + kb + q];
        float biN = bih[64 + kb + q];
        float bhN = bhh[64 + kb + q];
        float r0 = sigm(accR0[q] + bR);
        float z0 = sigm(accZ0[q] + bZ);
        float n0 = tanh_f(accI0[q] + biN + r0 * (accH0[q] + bhN));
        out0[q] = (1.f - z0) * n0 + z0 * hs0[q];
        float r1 = sigm(accR1[q] + bR);
        float z1 = sigm(accZ1[q] + bZ);
        float n1 = tanh_f(accI1[q] + biN + r1 * (accH1[q] + bhN));
        out1[q] = (1.f - z1) * n1 + z1 * hs1[q];
    }

    // zero agg slices for next step, then write h (all after every load)
    float4 z4 = make_float4(0.f, 0.f, 0.f, 0.f);
    ((float4*)a0)[j] = z4;
    ((float4*)a1)[j] = z4;
    ((float4*)h0p)[j] = make_float4(out0[0], out0[1], out0[2], out0[3]);
    ((float4*)h1p)[j] = make_float4(out1[0], out1[1], out1[2], out1[3]);
}

extern "C" void kernel_launch(void* const* d_in, const int* in_sizes, int n_in,
                              void* d_out, int out_size, void* d_ws, size_t ws_size,
                              hipStream_t stream) {
    const int*   node_ids  = (const int*)d_in[0];
    const int*   edge_ids  = (const int*)d_in[1];
    const int*   src       = (const int*)d_in[2];
    const int*   dst       = (const int*)d_in[3];
    const float* node_emb  = (const float*)d_in[4];
    const float* edge_emb  = (const float*)d_in[5];
    const float* proj_W    = (const float*)d_in[6];
    const float* proj_b    = (const float*)d_in[7];
    const float* eW1       = (const float*)d_in[8];
    const float* eb1       = (const float*)d_in[9];
    const float* eW2       = (const float*)d_in[10];
    const float* eb2       = (const float*)d_in[11];
    const float* conv_bias = (const float*)d_in[12];
    const float* gWih      = (const float*)d_in[13];
    const float* gWhh      = (const float*)d_in[14];
    const float* gbih      = (const float*)d_in[15];
    const float* gbhh      = (const float*)d_in[16];

    float* h = (float*)d_out;  // [N,32] fp32 — output buffer doubles as hidden state
    char* ws = (char*)d_ws;
    float* agg  = (float*)ws;                                  // 6,400,000 B
    float* Wt   = (float*)(ws + 6400 * 1024);                  // 86,016 B
    int*   hist = (int*)(ws + 6400 * 1024 + 128 * 1024);       // NB*NT = 2100
    int*   offs = hist + NB * NT;                              // 2100
    int*   cnt  = offs + NB * NT;                              // 32
    int*   base = cnt + 32;                                    // 32
    int*   perm = base + 32;                                   // 100,000

    hipMemsetAsync(agg, 0, (size_t)N_NODES * 32 * sizeof(float), stream);

    k_proj<<<(N_NODES + 7) / 8, 256, 0, stream>>>(node_ids, node_emb, proj_W, proj_b, h);
    k_wtable<<<NT * 8, 128, 0, stream>>>(edge_emb, eW1, eb1, eW2, eb2, Wt);
    k_hist<<<NB, 256, 0, stream>>>(edge_ids, hist);
    k_offs<<<1, 64, 0, stream>>>(hist, offs, cnt, base);
    k_fill2<<<NB, 256, 0, stream>>>(edge_ids, offs, base, perm);

    for (int s = 0; s < STEPS; ++s) {
        k_msg<<<NT * BPT, 256, 0, stream>>>(perm, base, cnt, src, dst, Wt, h, agg);
        k_gru<<<(N_NODES / 2 * 8 + 255) / 256, 256, 0, stream>>>(gWih, gWhh, gbih, gbhh, conv_bias, agg, h);
    }
}